// Round 2
// baseline (497.978 us; speedup 1.0000x reference)
//
#include <hip/hip_runtime.h>

// Blur: depthwise separable 4x4 ([1,3,3,1] outer [1,3,3,1] / 64)
// input  (8,256,64,512) fp32, W wrap-pad 1, H reflect-pad 1
// output (8,256,63,511) fp32
// Latency-bound fix (R1): 4 vertical chunks/image (4x TLP), unroll-4 row loop
// (4 row-loads in flight/wave), nontemporal stores (save L2/L3 for input).

constexpr int H_ = 64, W_ = 512;
constexpr int HO = 63, WO = 511;
constexpr int GROUPS = W_ / 4;   // 128 column-groups of 4 outputs
constexpr int NCHUNK = 4, CHUNK = 16;  // output rows per chunk (last chunk: 15)

// padded row p in 0..65 -> orig row (reflect: 0->1, 1..64->p-1, 65->62)
__device__ __forceinline__ int rowmap(int p) {
    int r = p - 1;
    if (p == 0)  r = 1;
    if (p > H_)  r = H_ - 2;
    return r;
}

// Horizontal blur of 4 consecutive outputs starting at col c0.
__device__ __forceinline__ float4 hblur_row(const float* __restrict__ row,
                                            int c0, int pcol, int bcol) {
    const float4 A  = *reinterpret_cast<const float4*>(row + c0);
    const float2 Bv = *reinterpret_cast<const float2*>(row + bcol);
    const float  p  = row[pcol];
    float4 r;
    r.x = fmaf(3.f, A.x + A.y, p   + A.z);
    r.y = fmaf(3.f, A.y + A.z, A.x + A.w);
    r.z = fmaf(3.f, A.z + A.w, A.y + Bv.x);
    r.w = fmaf(3.f, A.w + Bv.x, A.z + Bv.y);
    return r;
}

__global__ __launch_bounds__(256) void blur_kernel(const float* __restrict__ h,
                                                   float* __restrict__ out) {
    const int tid   = blockIdx.x * blockDim.x + threadIdx.x;
    const int g     = tid & (GROUPS - 1);          // 0..127 (lane-varying)
    const int chunk = (tid >> 7) & (NCHUNK - 1);   // wave-uniform
    const int bc    = tid >> 9;                    // image 0..2047, wave-uniform

    const float* img = h   + (size_t)bc * (H_ * W_);
    float*       op  = out + (size_t)bc * (HO * WO);

    const int c0   = g * 4;
    const int pcol = (c0 - 1) & (W_ - 1);
    const int bcol = (c0 + 4) & (W_ - 1);

    const int oy0 = chunk * CHUNK;
    const int R   = min(CHUNK, HO - oy0);          // 16,16,16,15

    float4 h0 = hblur_row(img + rowmap(oy0)     * W_, c0, pcol, bcol);
    float4 h1 = hblur_row(img + rowmap(oy0 + 1) * W_, c0, pcol, bcol);
    float4 h2 = hblur_row(img + rowmap(oy0 + 2) * W_, c0, pcol, bcol);

    const int nstore = (g == GROUPS - 1) ? 3 : 4;  // out width 511

    #pragma unroll 4
    for (int j = 0; j < R; ++j) {
        const int p3 = oy0 + j + 3;                // padded row 3..65
        const float4 h3 = hblur_row(img + rowmap(p3) * W_, c0, pcol, bcol);

        float o[4];
        o[0] = (h0.x + h3.x + 3.f * (h1.x + h2.x)) * (1.f / 64.f);
        o[1] = (h0.y + h3.y + 3.f * (h1.y + h2.y)) * (1.f / 64.f);
        o[2] = (h0.z + h3.z + 3.f * (h1.z + h2.z)) * (1.f / 64.f);
        o[3] = (h0.w + h3.w + 3.f * (h1.w + h2.w)) * (1.f / 64.f);

        float* dst = op + (size_t)(oy0 + j) * WO + c0;
        #pragma unroll
        for (int k = 0; k < 4; ++k)
            if (k < nstore) __builtin_nontemporal_store(o[k], dst + k);

        h0 = h1; h1 = h2; h2 = h3;
    }
}

extern "C" void kernel_launch(void* const* d_in, const int* in_sizes, int n_in,
                              void* d_out, int out_size, void* d_ws, size_t ws_size,
                              hipStream_t stream) {
    const float* h = (const float*)d_in[0];
    float* out = (float*)d_out;

    // 2048 images * 4 chunks * 128 groups = 1,048,576 threads
    const int total = 2048 * NCHUNK * GROUPS;
    const int block = 256;
    const int grid  = total / block;  // 4096
    blur_kernel<<<grid, block, 0, stream>>>(h, out);
}

// Round 4
// 459.120 us; speedup vs baseline: 1.0846x; 1.0846x over previous
//
#include <hip/hip_runtime.h>

// Blur: depthwise separable 4x4 ([1,3,3,1] outer [1,3,3,1] / 64)
// input (8,256,64,512) fp32, W wrap-pad, H reflect-pad -> output (8,256,63,511)
//
// R2: wave-per-row structure. Lane l owns cols 8l..8l+7; two coalesced float4
// loads per row (2KB contiguous per wave, each row read once). Horizontal
// neighbors via __shfl (wrap == lane wrap mod 64). Vertical via rolling
// 4-row register window. 4 row-bands/image -> 8192 waves = 32/CU.
// No nontemporal stores (R1: nt caused 1.44x write amplification).

constexpr int H_ = 64, W_ = 512;
constexpr int HO = 63, WO = 511;
constexpr int CHUNK = 16;   // output rows per band (band 3 overlaps: oy0=47)

struct F8 { float v[8]; };

// padded row p in 0..65 -> orig row (reflect: 0->1, 1..64->p-1, 65->62)
__device__ __forceinline__ int rowmap(int p) {
    int r = p - 1;
    if (p == 0)  r = 1;
    if (p > H_)  r = H_ - 2;
    return r;
}

// Horizontal [1,3,3,1] blur of this lane's 8 columns of one row.
__device__ __forceinline__ F8 hblur_row(const float* __restrict__ row, int lane) {
    const float4 Va = *reinterpret_cast<const float4*>(row + 8 * lane);
    const float4 Vb = *reinterpret_cast<const float4*>(row + 8 * lane + 4);
    // neighbors via lane shuffle; W-wrap == lane wrap mod 64
    const float left = __shfl(Vb.w, (lane + 63) & 63, 64);  // col 8l-1
    const float r0   = __shfl(Va.x, (lane + 1) & 63, 64);   // col 8l+8
    const float r1   = __shfl(Va.y, (lane + 1) & 63, 64);   // col 8l+9
    const float x[11] = {left, Va.x, Va.y, Va.z, Va.w,
                         Vb.x, Vb.y, Vb.z, Vb.w, r0, r1};
    F8 o;
    #pragma unroll
    for (int i = 0; i < 8; ++i)
        o.v[i] = fmaf(3.f, x[i + 1] + x[i + 2], x[i] + x[i + 3]);
    return o;
}

__global__ __launch_bounds__(256) void blur_kernel(const float* __restrict__ h,
                                                   float* __restrict__ out) {
    const int tid   = blockIdx.x * blockDim.x + threadIdx.x;
    const int lane  = tid & 63;
    const int wid   = tid >> 6;        // global wave id 0..8191
    const int band  = wid & 3;
    const int bc    = wid >> 2;        // image 0..2047

    const float* img = h   + (size_t)bc * (H_ * W_);
    float*       op  = out + (size_t)bc * (HO * WO);

    const int oy0 = (band < 3) ? band * CHUNK : HO - CHUNK;  // 0,16,32,47

    F8 h0 = hblur_row(img + rowmap(oy0)     * W_, lane);
    F8 h1 = hblur_row(img + rowmap(oy0 + 1) * W_, lane);
    F8 h2 = hblur_row(img + rowmap(oy0 + 2) * W_, lane);

    const int ncol = (lane == 63) ? 7 : 8;  // out width 511: last lane 7 cols

    #pragma unroll 4
    for (int j = 0; j < CHUNK; ++j) {
        const F8 h3 = hblur_row(img + rowmap(oy0 + j + 3) * W_, lane);
        float* dst = op + (size_t)(oy0 + j) * WO + 8 * lane;
        #pragma unroll
        for (int i = 0; i < 8; ++i) {
            const float o =
                (h0.v[i] + h3.v[i] + 3.f * (h1.v[i] + h2.v[i])) * (1.f / 64.f);
            if (i < ncol) dst[i] = o;
        }
        h0 = h1; h1 = h2; h2 = h3;
    }
}

extern "C" void kernel_launch(void* const* d_in, const int* in_sizes, int n_in,
                              void* d_out, int out_size, void* d_ws, size_t ws_size,
                              hipStream_t stream) {
    const float* h = (const float*)d_in[0];
    float* out = (float*)d_out;

    // 2048 images * 4 bands * 64 lanes = 524288 threads, 2048 blocks
    const int total = 2048 * 4 * 64;
    const int block = 256;
    const int grid  = total / block;
    blur_kernel<<<grid, block, 0, stream>>>(h, out);
}

// Round 5
// 446.261 us; speedup vs baseline: 1.1159x; 1.0288x over previous
//
#include <hip/hip_runtime.h>

// Blur: depthwise separable 4x4 ([1,3,3,1] outer [1,3,3,1] / 64)
// input (8,256,64,512) fp32, W wrap-pad, H reflect-pad -> output (8,256,63,511)
//
// R4: loads as R2 (lane owns cols 8l..8l+7, 2 coalesced dwordx4/row, shfl
// neighbors, rolling 4-row window). NEW: stores go through a wave-private
// LDS transpose (stride-9 pad, conflict-free) so each output row is written
// with 8 fully-coalesced lane-consecutive dword stores (dense cache lines)
// instead of 8 strided scalar stores (8B per 64B line). Double-buffered LDS.

constexpr int H_ = 64, W_ = 512;
constexpr int HO = 63, WO = 511;
constexpr int CHUNK = 16;          // band 3 overlaps one row (oy0=47); benign
constexpr int LSTRIDE = 9;         // padded lane stride in LDS floats
constexpr int LSZ = 64 * LSTRIDE;  // 576 floats per wave buffer

struct F8 { float v[8]; };

// padded row p in 0..65 -> orig row (reflect: 0->1, 1..64->p-1, 65->62)
__device__ __forceinline__ int rowmap(int p) {
    int r = p - 1;
    if (p == 0)  r = 1;
    if (p > H_)  r = H_ - 2;
    return r;
}

// Horizontal [1,3,3,1] blur of this lane's 8 columns of one row.
__device__ __forceinline__ F8 hblur_row(const float* __restrict__ row, int lane) {
    const float4 Va = *reinterpret_cast<const float4*>(row + 8 * lane);
    const float4 Vb = *reinterpret_cast<const float4*>(row + 8 * lane + 4);
    const float left = __shfl(Vb.w, (lane + 63) & 63, 64);  // col 8l-1 (wrap)
    const float r0   = __shfl(Va.x, (lane + 1) & 63, 64);   // col 8l+8 (wrap)
    const float r1   = __shfl(Va.y, (lane + 1) & 63, 64);   // col 8l+9 (wrap)
    const float x[11] = {left, Va.x, Va.y, Va.z, Va.w,
                         Vb.x, Vb.y, Vb.z, Vb.w, r0, r1};
    F8 o;
    #pragma unroll
    for (int i = 0; i < 8; ++i)
        o.v[i] = fmaf(3.f, x[i + 1] + x[i + 2], x[i] + x[i + 3]);
    return o;
}

__global__ __launch_bounds__(256) void blur_kernel(const float* __restrict__ h,
                                                   float* __restrict__ out) {
    // 4 waves/block * 2 buffers (double-buffer across j) * 576 floats = 18KB
    __shared__ float lds[4][2][LSZ];

    const int tid   = blockIdx.x * blockDim.x + threadIdx.x;
    const int lane  = tid & 63;
    const int wv    = (threadIdx.x >> 6);   // wave in block 0..3
    const int wid   = tid >> 6;             // global wave 0..8191
    const int band  = wid & 3;
    const int bc    = wid >> 2;             // image 0..2047

    const float* img = h   + (size_t)bc * (H_ * W_);
    float*       op  = out + (size_t)bc * (HO * WO);

    const int oy0 = (band < 3) ? band * CHUNK : HO - CHUNK;  // 0,16,32,47

    F8 h0 = hblur_row(img + rowmap(oy0)     * W_, lane);
    F8 h1 = hblur_row(img + rowmap(oy0 + 1) * W_, lane);
    F8 h2 = hblur_row(img + rowmap(oy0 + 2) * W_, lane);

    const int wbase = LSTRIDE * lane;                     // write base (this lane)
    const int rbase = LSTRIDE * (lane >> 3) + (lane & 7); // read base (transpose)

    #pragma unroll 4
    for (int j = 0; j < CHUNK; ++j) {
        const F8 h3 = hblur_row(img + rowmap(oy0 + j + 3) * W_, lane);

        float* myl = lds[wv][j & 1];
        #pragma unroll
        for (int i = 0; i < 8; ++i) {
            const float o =
                (h0.v[i] + h3.v[i] + 3.f * (h1.v[i] + h2.v[i])) * (1.f / 64.f);
            myl[wbase + i] = o;   // lane's cols 8l..8l+7, stride-9 padded
        }

        // Transposed read: lane gets cols {lane, 64+lane, ..., 448+lane}
        float* dst = op + (size_t)(oy0 + j) * WO;
        #pragma unroll
        for (int s = 0; s < 8; ++s) {
            const float val = myl[72 * s + rbase];
            const int c = 64 * s + lane;
            if (c < WO) dst[c] = val;   // lane-consecutive dense stores
        }

        h0 = h1; h1 = h2; h2 = h3;
    }
}

extern "C" void kernel_launch(void* const* d_in, const int* in_sizes, int n_in,
                              void* d_out, int out_size, void* d_ws, size_t ws_size,
                              hipStream_t stream) {
    const float* h = (const float*)d_in[0];
    float* out = (float*)d_out;

    // 2048 images * 4 bands * 64 lanes = 524288 threads, 2048 blocks
    const int total = 2048 * 4 * 64;
    const int block = 256;
    const int grid  = total / block;
    blur_kernel<<<grid, block, 0, stream>>>(h, out);
}